// Round 11
// baseline (1463.198 us; speedup 1.0000x reference)
//
#include <hip/hip_runtime.h>
#include <hip/hip_bf16.h>
#include <hip/hip_cooperative_groups.h>

namespace cg = cooperative_groups;

#define N_NODES 50000
#define N_EDGES 600000
#define DD 128
#define N_LAYERS 6
#define SCAN_BLOCKS 196   // ceil(50000/256)
#define N_CHUNKS 3125     // 50000 / 16 exactly
#define GEMM_BLOCKS 512   // 512 blocks x 8 waves = 4096 chunks >= 3125; 2 blocks/CU x 256 CU
#define HSTRIDE ((size_t)N_NODES * DD)   // 6.4M ushorts = 12.8 MB

#define XB16_T 1600000
#define PREPW_T 196608
#define PREP_TOTAL (XB16_T + PREPW_T + N_EDGES)

typedef __attribute__((ext_vector_type(8))) short bf16x8;
typedef __attribute__((ext_vector_type(4))) float floatx4;

__device__ __forceinline__ unsigned short f2b(float f) {
    unsigned u = __float_as_uint(f);
    unsigned r = (u + 0x7FFFu + ((u >> 16) & 1u)) >> 16;
    return (unsigned short)r;
}

// ---------------- merged prep (x->bf16, W transpose, count_deg) ----------------

__global__ void prep_all(const float* __restrict__ x, unsigned short* __restrict__ hx,
                         const float* __restrict__ Wl, const float* __restrict__ Wr,
                         unsigned short* __restrict__ WT2,
                         const int* __restrict__ dst, int* __restrict__ deg) {
    int gid = blockIdx.x * blockDim.x + threadIdx.x;
    if (gid < XB16_T) {
        int b = gid * 4;
        float4 v = *(const float4*)(x + b);
        ushort4 o;
        o.x = f2b(v.x); o.y = f2b(v.y); o.z = f2b(v.z); o.w = f2b(v.w);
        *(ushort4*)(hx + b) = o;
    } else if (gid < XB16_T + PREPW_T) {
        int idx = gid - XB16_T;
        int l   = idx >> 15;
        int rem = idx & 32767;
        int n   = rem >> 8;
        int k2  = rem & 255;
        const float* W = (k2 < 128 ? Wl : Wr) + (size_t)l * DD * DD + (size_t)(k2 & 127) * DD + n;
        WT2[idx] = f2b(*W);
    } else if (gid < PREP_TOTAL) {
        int e = gid - (XB16_T + PREPW_T);
        atomicAdd(&deg[dst[e]], 1);
    }
}

// ---------------- CSR build (multi-block, proven-fast) ----------------

__global__ void block_sums(const int* __restrict__ deg, int* __restrict__ bsum) {
    __shared__ int s[256];
    int tid = threadIdx.x;
    int i = blockIdx.x * 256 + tid;
    int v = (i < N_NODES) ? deg[i] : 0;
    s[tid] = v;
    __syncthreads();
    #pragma unroll
    for (int off = 128; off > 0; off >>= 1) {
        if (tid < off) s[tid] += s[tid + off];
        __syncthreads();
    }
    if (tid == 0) bsum[blockIdx.x] = s[0];
}

__global__ void scan_bsums(int* __restrict__ bsum, int* __restrict__ offsets) {
    __shared__ int s[256];
    int tid = threadIdx.x;
    int v = (tid < SCAN_BLOCKS) ? bsum[tid] : 0;
    s[tid] = v;
    __syncthreads();
    for (int off = 1; off < 256; off <<= 1) {
        int t = (tid >= off) ? s[tid - off] : 0;
        __syncthreads();
        s[tid] += t;
        __syncthreads();
    }
    if (tid < SCAN_BLOCKS) bsum[tid] = s[tid] - v;   // exclusive
    if (tid == 0) offsets[N_NODES] = N_EDGES;
}

__global__ void write_offsets(const int* __restrict__ deg, const int* __restrict__ bsum,
                              int* __restrict__ offsets, float* __restrict__ deg_inv) {
    __shared__ int s[256];
    int tid = threadIdx.x;
    int i = blockIdx.x * 256 + tid;
    int v = (i < N_NODES) ? deg[i] : 0;
    s[tid] = v;
    __syncthreads();
    for (int off = 1; off < 256; off <<= 1) {
        int t = (tid >= off) ? s[tid - off] : 0;
        __syncthreads();
        s[tid] += t;
        __syncthreads();
    }
    if (i < N_NODES) {
        offsets[i] = bsum[blockIdx.x] + s[tid] - v;
        deg_inv[i] = 1.0f / (float)(v > 1 ? v : 1);
    }
}

__global__ void fill_csr(const int* __restrict__ src, const int* __restrict__ dst,
                         const int* __restrict__ offsets, int* __restrict__ cursor,
                         int* __restrict__ csr_src) {
    int e = blockIdx.x * blockDim.x + threadIdx.x;
    if (e < N_EDGES) {
        int d = dst[e];
        int p = atomicAdd(&cursor[d], 1);
        csr_src[offsets[d] + p] = src[e];
    }
}

// ---------------- shared layer body (R9-proven) ----------------

__device__ __forceinline__ void acc8(float* a, const uint4& v) {
    a[0] += __uint_as_float(v.x << 16); a[1] += __uint_as_float(v.x & 0xFFFF0000u);
    a[2] += __uint_as_float(v.y << 16); a[3] += __uint_as_float(v.y & 0xFFFF0000u);
    a[4] += __uint_as_float(v.z << 16); a[5] += __uint_as_float(v.z & 0xFFFF0000u);
    a[6] += __uint_as_float(v.w << 16); a[7] += __uint_as_float(v.w & 0xFFFF0000u);
}

__device__ __forceinline__ void layer_body(
        unsigned short* sW, int tid, int l15, int q,
        bool active, int row0, int node, int s0, int e0, float di,
        const unsigned short* __restrict__ hin,
        const int* __restrict__ csr_src,
        const unsigned short* __restrict__ WT2,
        const float* __restrict__ bias,
        unsigned short* __restrict__ hout,
        const float* __restrict__ fcW,
        const float* __restrict__ fcb,
        float* __restrict__ out, int doFC) {
    // ---- fill sW (swizzled: chunk c of col stored at col*32 + (c ^ (col&7))) ----
    for (int t = tid; t < 4096; t += 512) {
        int col = t >> 5, c = t & 31;
        uint4 v = *(const uint4*)(WT2 + (size_t)col * 256 + c * 8);
        *(uint4*)(sW + ((size_t)col * 32 + (c ^ (col & 7))) * 8) = v;
    }
    __syncthreads();

    // ---- in-register aggregation of this lane's A-fragment features ----
    float a[32];
    #pragma unroll
    for (int i = 0; i < 32; ++i) a[i] = 0.f;

    const unsigned short* hbase = hin + q * 8;
    int j = s0;
    for (; j + 1 < e0; j += 2) {
        int src1 = csr_src[j];
        int src2 = csr_src[j + 1];
        const unsigned short* r1 = hbase + (size_t)src1 * DD;
        const unsigned short* r2 = hbase + (size_t)src2 * DD;
        uint4 v0 = *(const uint4*)(r1);
        uint4 v1 = *(const uint4*)(r1 + 32);
        uint4 v2 = *(const uint4*)(r1 + 64);
        uint4 v3 = *(const uint4*)(r1 + 96);
        uint4 w0 = *(const uint4*)(r2);
        uint4 w1 = *(const uint4*)(r2 + 32);
        uint4 w2 = *(const uint4*)(r2 + 64);
        uint4 w3 = *(const uint4*)(r2 + 96);
        acc8(a +  0, v0); acc8(a +  8, v1); acc8(a + 16, v2); acc8(a + 24, v3);
        acc8(a +  0, w0); acc8(a +  8, w1); acc8(a + 16, w2); acc8(a + 24, w3);
    }
    if (j < e0) {
        int src1 = csr_src[j];
        const unsigned short* r1 = hbase + (size_t)src1 * DD;
        uint4 v0 = *(const uint4*)(r1);
        uint4 v1 = *(const uint4*)(r1 + 32);
        uint4 v2 = *(const uint4*)(r1 + 64);
        uint4 v3 = *(const uint4*)(r1 + 96);
        acc8(a +  0, v0); acc8(a +  8, v1); acc8(a + 16, v2); acc8(a + 24, v3);
    }

    // ---- pack A-fragments: agg (s<4, bf16-rounded mean) and root H (s>=4) ----
    bf16x8 aF[8];
    #pragma unroll
    for (int s = 0; s < 4; ++s) {
        bf16x8 f;
        #pragma unroll
        for (int k = 0; k < 8; ++k) f[k] = (short)f2b(a[s * 8 + k] * di);
        aF[s] = f;
    }
    const unsigned short* Hrow = hin + (size_t)node * DD;
    #pragma unroll
    for (int s = 4; s < 8; ++s)
        aF[s] = *(const bf16x8*)(Hrow + (s - 4) * 32 + q * 8);

    float bcol[8];
    #pragma unroll
    for (int jj = 0; jj < 8; ++jj) bcol[jj] = bias[jj * 16 + l15];

    floatx4 acc[8];
    #pragma unroll
    for (int jj = 0; jj < 8; ++jj) acc[jj] = (floatx4){0.f, 0.f, 0.f, 0.f};

    #pragma unroll
    for (int s = 0; s < 8; ++s) {
        int cglob = s * 4 + q;
        #pragma unroll
        for (int jj = 0; jj < 8; ++jj) {
            int col = jj * 16 + l15;
            bf16x8 bF = *(const bf16x8*)(sW + ((size_t)col * 32 + (cglob ^ (col & 7))) * 8);
            acc[jj] = __builtin_amdgcn_mfma_f32_16x16x32_bf16(aF[s], bF, acc[jj], 0, 0, 0);
        }
    }

    if (!doFC) {
        if (active) {
            #pragma unroll
            for (int r = 0; r < 4; ++r) {
                int row = row0 + q * 4 + r;
                #pragma unroll
                for (int jj = 0; jj < 8; ++jj) {
                    float v = acc[jj][r] + bcol[jj];
                    hout[(size_t)row * DD + jj * 16 + l15] = f2b(fmaxf(v, 0.f));
                }
            }
        }
    } else {
        float2 fcw[8];
        #pragma unroll
        for (int jj = 0; jj < 8; ++jj) fcw[jj] = *(const float2*)(fcW + (jj * 16 + l15) * 2);
        float fb0 = fcb[0], fb1 = fcb[1];
        #pragma unroll
        for (int r = 0; r < 4; ++r) {
            float p0 = 0.f, p1 = 0.f;
            #pragma unroll
            for (int jj = 0; jj < 8; ++jj) {
                float v = fmaxf(acc[jj][r] + bcol[jj], 0.f);
                p0 += v * fcw[jj].x;
                p1 += v * fcw[jj].y;
            }
            p0 += __shfl_xor(p0, 1, 64); p1 += __shfl_xor(p1, 1, 64);
            p0 += __shfl_xor(p0, 2, 64); p1 += __shfl_xor(p1, 2, 64);
            p0 += __shfl_xor(p0, 4, 64); p1 += __shfl_xor(p1, 4, 64);
            p0 += __shfl_xor(p0, 8, 64); p1 += __shfl_xor(p1, 8, 64);
            if (l15 == 0 && active) {
                int row = row0 + q * 4 + r;
                out[row * 2]     = p0 + fb0;
                out[row * 2 + 1] = p1 + fb1;
            }
        }
    }
}

// ---------------- fallback: one layer per dispatch (R9-proven, 343.6 us) ----------------

__launch_bounds__(512, 4)
__global__ void sage_layer(const unsigned short* __restrict__ hin,
                           const int* __restrict__ offsets,
                           const int* __restrict__ csr_src,
                           const float* __restrict__ deg_inv,
                           const unsigned short* __restrict__ WT2,
                           const float* __restrict__ bias,
                           unsigned short* __restrict__ hout,
                           const float* __restrict__ fcW,
                           const float* __restrict__ fcb,
                           float* __restrict__ out,
                           int doFC) {
    __shared__ __align__(16) unsigned short sW[128 * 256];     // 64 KB
    int tid  = threadIdx.x;
    int wid  = tid >> 6, lane = tid & 63;
    int l15  = lane & 15, q = lane >> 4;
    int chunk = wid * GEMM_BLOCKS + (int)blockIdx.x;
    bool active = chunk < N_CHUNKS;
    int chunkC = active ? chunk : N_CHUNKS - 1;
    int row0 = chunkC * 16;
    int node = row0 + l15;
    int s0 = active ? offsets[node]     : 0;
    int e0 = active ? offsets[node + 1] : 0;
    float di = deg_inv[node];
    layer_body(sW, tid, l15, q, active, row0, node, s0, e0, di,
               hin, csr_src, WT2, bias, hout, fcW, fcb, out, doFC);
}

// ---------------- cooperative: all 6 layers, grid.sync between ----------------
// RACE-FREE BY CONSTRUCTION: each of the 5 intermediate buffers (hbuf + l*HSTRIDE)
// is written exactly once before any read within this dispatch -> no XCD can hold
// a stale L2 copy of lines it never touched. threadfence (device writeback) before
// grid.sync; explicit agent-scope acquire fence (L2 invalidate) after.

__launch_bounds__(512, 4)
__global__ void sage_all(const unsigned short* __restrict__ hx,
                         const int* __restrict__ offsets,
                         const int* __restrict__ csr_src,
                         const float* __restrict__ deg_inv,
                         const unsigned short* __restrict__ WT2all,
                         const float* __restrict__ blall,
                         unsigned short* __restrict__ hbuf,   // 5 x HSTRIDE
                         const float* __restrict__ fcW,
                         const float* __restrict__ fcb,
                         float* __restrict__ out) {
    cg::grid_group grid = cg::this_grid();
    __shared__ __align__(16) unsigned short sW[128 * 256];     // 64 KB

    int tid  = threadIdx.x;
    int wid  = tid >> 6, lane = tid & 63;
    int l15  = lane & 15, q = lane >> 4;
    int chunk = wid * GEMM_BLOCKS + (int)blockIdx.x;
    bool active = chunk < N_CHUNKS;
    int chunkC = active ? chunk : N_CHUNKS - 1;
    int row0 = chunkC * 16;
    int node = row0 + l15;
    int s0 = active ? offsets[node]     : 0;
    int e0 = active ? offsets[node + 1] : 0;
    float di = deg_inv[node];

    const unsigned short* hin = hx;
    for (int l = 0; l < N_LAYERS; ++l) {
        int doFC = (l == N_LAYERS - 1);
        unsigned short* hout = doFC ? (unsigned short*)nullptr : hbuf + (size_t)l * HSTRIDE;
        layer_body(sW, tid, l15, q, active, row0, node, s0, e0, di,
                   hin, csr_src, WT2all + (size_t)l * 128 * 256,
                   blall + (size_t)l * DD, hout, fcW, fcb, out, doFC);
        if (l < N_LAYERS - 1) {
            __threadfence();                                   // device-scope writeback
            grid.sync();
            __builtin_amdgcn_fence(__ATOMIC_ACQUIRE, "agent"); // L2 invalidate (belt+braces)
            hin = hout;
        }
    }
}

// ---------------- launch ----------------

extern "C" void kernel_launch(void* const* d_in, const int* in_sizes, int n_in,
                              void* d_out, int out_size, void* d_ws, size_t ws_size,
                              hipStream_t stream) {
    const float* x    = (const float*)d_in[0];
    const int*   ei   = (const int*)d_in[1];
    const float* Wl   = (const float*)d_in[2];
    const float* Wr   = (const float*)d_in[3];
    const float* bl   = (const float*)d_in[4];
    const float* fcW  = (const float*)d_in[5];
    const float* fcb  = (const float*)d_in[6];
    float* out = (float*)d_out;

    const int* srcIdx = ei;
    const int* dstIdx = ei + N_EDGES;

    char* ws = (char*)d_ws;
    size_t off = 0;
    auto bump = [&](size_t bytes) { char* p = ws + off; off = (off + bytes + 255) & ~(size_t)255; return p; };
    int*   deg     = (int*)  bump(N_NODES * 4);
    int*   cursor  = (int*)  bump(N_NODES * 4);
    int*   offsets = (int*)  bump((N_NODES + 1) * 4);
    int*   bsum    = (int*)  bump(SCAN_BLOCKS * 4);
    float* deg_inv = (float*)bump(N_NODES * 4);
    int*   csr     = (int*)  bump(N_EDGES * 4);
    unsigned short* hx   = (unsigned short*)bump(HSTRIDE * 2);
    unsigned short* hbuf = (unsigned short*)bump(HSTRIDE * 2 * 5);   // 5 fresh layer buffers
    unsigned short* WT2  = (unsigned short*)bump((size_t)N_LAYERS * 128 * 256 * 2);
    (void)ws_size;

    // zero deg+cursor (contiguous in ws) via one stream-ordered memset (~0.4 MB)
    size_t zbytes = (size_t)((char*)cursor - (char*)deg) + (size_t)N_NODES * 4;
    (void)hipMemsetAsync(deg, 0, zbytes, stream);

    prep_all<<<(PREP_TOTAL + 255) / 256, 256, 0, stream>>>(x, hx, Wl, Wr, WT2, dstIdx, deg);
    block_sums<<<SCAN_BLOCKS, 256, 0, stream>>>(deg, bsum);
    scan_bsums<<<1, 256, 0, stream>>>(bsum, offsets);
    write_offsets<<<SCAN_BLOCKS, 256, 0, stream>>>(deg, bsum, offsets, deg_inv);
    fill_csr<<<(N_EDGES + 255) / 256, 256, 0, stream>>>(srcIdx, dstIdx, offsets, cursor, csr);

    const unsigned short* hx_c = hx;
    const int* offsets_c = offsets;
    const int* csr_c = csr;
    const float* deg_inv_c = deg_inv;
    const unsigned short* WT2_c = WT2;
    unsigned short* hbuf_c = hbuf;
    void* args[] = {
        (void*)&hx_c, (void*)&offsets_c, (void*)&csr_c, (void*)&deg_inv_c,
        (void*)&WT2_c, (void*)&bl, (void*)&hbuf_c, (void*)&fcW, (void*)&fcb, (void*)&out
    };
    hipError_t ce = hipLaunchCooperativeKernel((const void*)sage_all, dim3(GEMM_BLOCKS),
                                               dim3(512), args, 0, stream);
    if (ce != hipSuccess) {
        // fallback: proven per-layer path (R9, 343.6 us)
        const unsigned short* hin = hx;
        for (int l = 0; l < N_LAYERS; ++l) {
            int last = (l == N_LAYERS - 1);
            unsigned short* hout = hbuf + (size_t)(l < 5 ? l : 0) * HSTRIDE;
            sage_layer<<<GEMM_BLOCKS, 512, 0, stream>>>(
                hin, offsets, csr, deg_inv, WT2 + (size_t)l * 128 * 256,
                bl + (size_t)l * DD, hout, fcW, fcb, out, last);
            hin = hout;
        }
    }
}

// Round 12
// 379.406 us; speedup vs baseline: 3.8565x; 3.8565x over previous
//
#include <hip/hip_runtime.h>
#include <hip/hip_bf16.h>

#define N_NODES 50000
#define N_EDGES 600000
#define DD 128
#define N_LAYERS 6
#define SCAN_BLOCKS 196   // ceil(50000/256)
#define N_CHUNKS 3125     // 50000 / 16 exactly
#define GEMM_BLOCKS 512   // 512 blocks x 8 waves = 4096 chunks >= 3125

#define XB16_T 1600000
#define PREPW_T 196608
#define PREP_TOTAL (XB16_T + PREPW_T + N_EDGES)

typedef __attribute__((ext_vector_type(8))) short bf16x8;
typedef __attribute__((ext_vector_type(4))) float floatx4;

__device__ __forceinline__ unsigned short f2b(float f) {
    unsigned u = __float_as_uint(f);
    unsigned r = (u + 0x7FFFu + ((u >> 16) & 1u)) >> 16;
    return (unsigned short)r;
}

// ---------------- merged prep (x->bf16, W transpose, count_deg) ----------------
// deg/cursor are zeroed by one hipMemsetAsync before this kernel.

__global__ void prep_all(const float* __restrict__ x, unsigned short* __restrict__ hx,
                         const float* __restrict__ Wl, const float* __restrict__ Wr,
                         unsigned short* __restrict__ WT2,
                         const int* __restrict__ dst, int* __restrict__ deg) {
    int gid = blockIdx.x * blockDim.x + threadIdx.x;
    if (gid < XB16_T) {
        int b = gid * 4;
        float4 v = *(const float4*)(x + b);
        ushort4 o;
        o.x = f2b(v.x); o.y = f2b(v.y); o.z = f2b(v.z); o.w = f2b(v.w);
        *(ushort4*)(hx + b) = o;
    } else if (gid < XB16_T + PREPW_T) {
        int idx = gid - XB16_T;
        int l   = idx >> 15;
        int rem = idx & 32767;
        int n   = rem >> 8;
        int k2  = rem & 255;
        const float* W = (k2 < 128 ? Wl : Wr) + (size_t)l * DD * DD + (size_t)(k2 & 127) * DD + n;
        WT2[idx] = f2b(*W);
    } else if (gid < PREP_TOTAL) {
        int e = gid - (XB16_T + PREPW_T);
        atomicAdd(&deg[dst[e]], 1);
    }
}

// ---------------- CSR build (multi-block, proven-fast) ----------------

__global__ void block_sums(const int* __restrict__ deg, int* __restrict__ bsum) {
    __shared__ int s[256];
    int tid = threadIdx.x;
    int i = blockIdx.x * 256 + tid;
    int v = (i < N_NODES) ? deg[i] : 0;
    s[tid] = v;
    __syncthreads();
    #pragma unroll
    for (int off = 128; off > 0; off >>= 1) {
        if (tid < off) s[tid] += s[tid + off];
        __syncthreads();
    }
    if (tid == 0) bsum[blockIdx.x] = s[0];
}

__global__ void scan_bsums(int* __restrict__ bsum, int* __restrict__ offsets) {
    __shared__ int s[256];
    int tid = threadIdx.x;
    int v = (tid < SCAN_BLOCKS) ? bsum[tid] : 0;
    s[tid] = v;
    __syncthreads();
    for (int off = 1; off < 256; off <<= 1) {
        int t = (tid >= off) ? s[tid - off] : 0;
        __syncthreads();
        s[tid] += t;
        __syncthreads();
    }
    if (tid < SCAN_BLOCKS) bsum[tid] = s[tid] - v;   // exclusive
    if (tid == 0) offsets[N_NODES] = N_EDGES;
}

__global__ void write_offsets(const int* __restrict__ deg, const int* __restrict__ bsum,
                              int* __restrict__ offsets, float* __restrict__ deg_inv) {
    __shared__ int s[256];
    int tid = threadIdx.x;
    int i = blockIdx.x * 256 + tid;
    int v = (i < N_NODES) ? deg[i] : 0;
    s[tid] = v;
    __syncthreads();
    for (int off = 1; off < 256; off <<= 1) {
        int t = (tid >= off) ? s[tid - off] : 0;
        __syncthreads();
        s[tid] += t;
        __syncthreads();
    }
    if (i < N_NODES) {
        offsets[i] = bsum[blockIdx.x] + s[tid] - v;
        deg_inv[i] = 1.0f / (float)(v > 1 ? v : 1);
    }
}

__global__ void fill_csr(const int* __restrict__ src, const int* __restrict__ dst,
                         const int* __restrict__ offsets, int* __restrict__ cursor,
                         int* __restrict__ csr_src) {
    int e = blockIdx.x * blockDim.x + threadIdx.x;
    if (e < N_EDGES) {
        int d = dst[e];
        int p = atomicAdd(&cursor[d], 1);
        csr_src[offsets[d] + p] = src[e];
    }
}

// ---------------- FUSED layer: gather-aggregate in registers + MFMA ----------------
// R9-proven structure (343.6 us). Gather deepened to 4 edges in flight; adds
// remain strictly in edge order (j, j+1, j+2, j+3) -> BITWISE-identical output
// to the 2-deep version. 16 outstanding 16-B loads/lane during gather.

__device__ __forceinline__ void acc8(float* a, const uint4& v) {
    a[0] += __uint_as_float(v.x << 16); a[1] += __uint_as_float(v.x & 0xFFFF0000u);
    a[2] += __uint_as_float(v.y << 16); a[3] += __uint_as_float(v.y & 0xFFFF0000u);
    a[4] += __uint_as_float(v.z << 16); a[5] += __uint_as_float(v.z & 0xFFFF0000u);
    a[6] += __uint_as_float(v.w << 16); a[7] += __uint_as_float(v.w & 0xFFFF0000u);
}

__launch_bounds__(512, 4)
__global__ void sage_layer(const unsigned short* __restrict__ hin,
                           const int* __restrict__ offsets,
                           const int* __restrict__ csr_src,
                           const float* __restrict__ deg_inv,
                           const unsigned short* __restrict__ WT2,   // [128 n][256 k]
                           const float* __restrict__ bias,
                           unsigned short* __restrict__ hout,
                           const float* __restrict__ fcW,
                           const float* __restrict__ fcb,
                           float* __restrict__ out,
                           int doFC) {
    __shared__ __align__(16) unsigned short sW[128 * 256];     // 64 KB

    int tid  = threadIdx.x;
    int wid  = tid >> 6, lane = tid & 63;
    int l15  = lane & 15, q = lane >> 4;

    // ---- fill sW (swizzled: chunk c of col stored at col*32 + (c ^ (col&7))) ----
    for (int t = tid; t < 4096; t += 512) {
        int col = t >> 5, c = t & 31;
        uint4 v = *(const uint4*)(WT2 + (size_t)col * 256 + c * 8);
        *(uint4*)(sW + ((size_t)col * 32 + (c ^ (col & 7))) * 8) = v;
    }
    __syncthreads();

    int chunk = wid * GEMM_BLOCKS + (int)blockIdx.x;
    bool active = chunk < N_CHUNKS;
    int chunkC = active ? chunk : N_CHUNKS - 1;   // clamped -> safe addresses
    int row0 = chunkC * 16;
    int node = row0 + l15;

    // ---- in-register aggregation of this lane's A-fragment features ----
    float a[32];
    #pragma unroll
    for (int i = 0; i < 32; ++i) a[i] = 0.f;

    int s0 = active ? offsets[node]     : 0;
    int e0 = active ? offsets[node + 1] : 0;
    float di = deg_inv[node];

    const unsigned short* hbase = hin + q * 8;
    int j = s0;
    // 4 edges in flight; adds strictly in edge order -> bitwise-identical sums
    for (; j + 3 < e0; j += 4) {
        int src1 = csr_src[j];
        int src2 = csr_src[j + 1];
        int src3 = csr_src[j + 2];
        int src4 = csr_src[j + 3];
        const unsigned short* r1 = hbase + (size_t)src1 * DD;
        const unsigned short* r2 = hbase + (size_t)src2 * DD;
        const unsigned short* r3 = hbase + (size_t)src3 * DD;
        const unsigned short* r4 = hbase + (size_t)src4 * DD;
        uint4 v0 = *(const uint4*)(r1);
        uint4 v1 = *(const uint4*)(r1 + 32);
        uint4 v2 = *(const uint4*)(r1 + 64);
        uint4 v3 = *(const uint4*)(r1 + 96);
        uint4 w0 = *(const uint4*)(r2);
        uint4 w1 = *(const uint4*)(r2 + 32);
        uint4 w2 = *(const uint4*)(r2 + 64);
        uint4 w3 = *(const uint4*)(r2 + 96);
        uint4 x0 = *(const uint4*)(r3);
        uint4 x1 = *(const uint4*)(r3 + 32);
        uint4 x2 = *(const uint4*)(r3 + 64);
        uint4 x3 = *(const uint4*)(r3 + 96);
        uint4 y0 = *(const uint4*)(r4);
        uint4 y1 = *(const uint4*)(r4 + 32);
        uint4 y2 = *(const uint4*)(r4 + 64);
        uint4 y3 = *(const uint4*)(r4 + 96);
        acc8(a +  0, v0); acc8(a +  8, v1); acc8(a + 16, v2); acc8(a + 24, v3);
        acc8(a +  0, w0); acc8(a +  8, w1); acc8(a + 16, w2); acc8(a + 24, w3);
        acc8(a +  0, x0); acc8(a +  8, x1); acc8(a + 16, x2); acc8(a + 24, x3);
        acc8(a +  0, y0); acc8(a +  8, y1); acc8(a + 16, y2); acc8(a + 24, y3);
    }
    if (j + 1 < e0) {
        int src1 = csr_src[j];
        int src2 = csr_src[j + 1];
        const unsigned short* r1 = hbase + (size_t)src1 * DD;
        const unsigned short* r2 = hbase + (size_t)src2 * DD;
        uint4 v0 = *(const uint4*)(r1);
        uint4 v1 = *(const uint4*)(r1 + 32);
        uint4 v2 = *(const uint4*)(r1 + 64);
        uint4 v3 = *(const uint4*)(r1 + 96);
        uint4 w0 = *(const uint4*)(r2);
        uint4 w1 = *(const uint4*)(r2 + 32);
        uint4 w2 = *(const uint4*)(r2 + 64);
        uint4 w3 = *(const uint4*)(r2 + 96);
        acc8(a +  0, v0); acc8(a +  8, v1); acc8(a + 16, v2); acc8(a + 24, v3);
        acc8(a +  0, w0); acc8(a +  8, w1); acc8(a + 16, w2); acc8(a + 24, w3);
        j += 2;
    }
    if (j < e0) {
        int src1 = csr_src[j];
        const unsigned short* r1 = hbase + (size_t)src1 * DD;
        uint4 v0 = *(const uint4*)(r1);
        uint4 v1 = *(const uint4*)(r1 + 32);
        uint4 v2 = *(const uint4*)(r1 + 64);
        uint4 v3 = *(const uint4*)(r1 + 96);
        acc8(a +  0, v0); acc8(a +  8, v1); acc8(a + 16, v2); acc8(a + 24, v3);
    }

    // ---- pack A-fragments: agg (s<4, bf16-rounded mean) and root H (s>=4) ----
    bf16x8 aF[8];
    #pragma unroll
    for (int s = 0; s < 4; ++s) {
        bf16x8 f;
        #pragma unroll
        for (int k = 0; k < 8; ++k) f[k] = (short)f2b(a[s * 8 + k] * di);
        aF[s] = f;
    }
    const unsigned short* Hrow = hin + (size_t)node * DD;
    #pragma unroll
    for (int s = 4; s < 8; ++s)
        aF[s] = *(const bf16x8*)(Hrow + (s - 4) * 32 + q * 8);

    float bcol[8];
    #pragma unroll
    for (int jj = 0; jj < 8; ++jj) bcol[jj] = bias[jj * 16 + l15];

    floatx4 acc[8];
    #pragma unroll
    for (int jj = 0; jj < 8; ++jj) acc[jj] = (floatx4){0.f, 0.f, 0.f, 0.f};

    #pragma unroll
    for (int s = 0; s < 8; ++s) {
        int cglob = s * 4 + q;
        #pragma unroll
        for (int jj = 0; jj < 8; ++jj) {
            int col = jj * 16 + l15;
            bf16x8 bF = *(const bf16x8*)(sW + ((size_t)col * 32 + (cglob ^ (col & 7))) * 8);
            acc[jj] = __builtin_amdgcn_mfma_f32_16x16x32_bf16(aF[s], bF, acc[jj], 0, 0, 0);
        }
    }

    if (!doFC) {
        if (active) {
            #pragma unroll
            for (int r = 0; r < 4; ++r) {
                int row = row0 + q * 4 + r;
                #pragma unroll
                for (int jj = 0; jj < 8; ++jj) {
                    float v = acc[jj][r] + bcol[jj];
                    hout[(size_t)row * DD + jj * 16 + l15] = f2b(fmaxf(v, 0.f));
                }
            }
        }
    } else {
        float2 fcw[8];
        #pragma unroll
        for (int jj = 0; jj < 8; ++jj) fcw[jj] = *(const float2*)(fcW + (jj * 16 + l15) * 2);
        float fb0 = fcb[0], fb1 = fcb[1];
        #pragma unroll
        for (int r = 0; r < 4; ++r) {
            float p0 = 0.f, p1 = 0.f;
            #pragma unroll
            for (int jj = 0; jj < 8; ++jj) {
                float v = fmaxf(acc[jj][r] + bcol[jj], 0.f);
                p0 += v * fcw[jj].x;
                p1 += v * fcw[jj].y;
            }
            p0 += __shfl_xor(p0, 1, 64); p1 += __shfl_xor(p1, 1, 64);
            p0 += __shfl_xor(p0, 2, 64); p1 += __shfl_xor(p1, 2, 64);
            p0 += __shfl_xor(p0, 4, 64); p1 += __shfl_xor(p1, 4, 64);
            p0 += __shfl_xor(p0, 8, 64); p1 += __shfl_xor(p1, 8, 64);
            if (l15 == 0 && active) {
                int row = row0 + q * 4 + r;
                out[row * 2]     = p0 + fb0;
                out[row * 2 + 1] = p1 + fb1;
            }
        }
    }
}

// ---------------- launch ----------------

extern "C" void kernel_launch(void* const* d_in, const int* in_sizes, int n_in,
                              void* d_out, int out_size, void* d_ws, size_t ws_size,
                              hipStream_t stream) {
    const float* x    = (const float*)d_in[0];
    const int*   ei   = (const int*)d_in[1];
    const float* Wl   = (const float*)d_in[2];
    const float* Wr   = (const float*)d_in[3];
    const float* bl   = (const float*)d_in[4];
    const float* fcW  = (const float*)d_in[5];
    const float* fcb  = (const float*)d_in[6];
    float* out = (float*)d_out;

    const int* srcIdx = ei;
    const int* dstIdx = ei + N_EDGES;

    char* ws = (char*)d_ws;
    size_t off = 0;
    auto bump = [&](size_t bytes) { char* p = ws + off; off = (off + bytes + 255) & ~(size_t)255; return p; };
    int*   deg     = (int*)  bump(N_NODES * 4);
    int*   cursor  = (int*)  bump(N_NODES * 4);
    int*   offsets = (int*)  bump((N_NODES + 1) * 4);
    int*   bsum    = (int*)  bump(SCAN_BLOCKS * 4);
    float* deg_inv = (float*)bump(N_NODES * 4);
    int*   csr     = (int*)  bump(N_EDGES * 4);
    unsigned short* hx   = (unsigned short*)bump((size_t)N_NODES * DD * 2);
    unsigned short* hb0  = (unsigned short*)bump((size_t)N_NODES * DD * 2);
    unsigned short* hb1  = (unsigned short*)bump((size_t)N_NODES * DD * 2);
    unsigned short* WT2  = (unsigned short*)bump((size_t)N_LAYERS * 128 * 256 * 2);
    (void)ws_size;

    // zero deg+cursor (contiguous in ws) via one stream-ordered memset (~0.4 MB)
    size_t zbytes = (size_t)((char*)cursor - (char*)deg) + (size_t)N_NODES * 4;
    (void)hipMemsetAsync(deg, 0, zbytes, stream);

    prep_all<<<(PREP_TOTAL + 255) / 256, 256, 0, stream>>>(x, hx, Wl, Wr, WT2, dstIdx, deg);
    block_sums<<<SCAN_BLOCKS, 256, 0, stream>>>(deg, bsum);
    scan_bsums<<<1, 256, 0, stream>>>(bsum, offsets);
    write_offsets<<<SCAN_BLOCKS, 256, 0, stream>>>(deg, bsum, offsets, deg_inv);
    fill_csr<<<(N_EDGES + 255) / 256, 256, 0, stream>>>(srcIdx, dstIdx, offsets, cursor, csr);

    const unsigned short* hin = hx;
    unsigned short* hbuf[2] = { hb0, hb1 };
    for (int l = 0; l < N_LAYERS; ++l) {
        int last = (l == N_LAYERS - 1);
        unsigned short* hout = hbuf[l & 1];
        sage_layer<<<GEMM_BLOCKS, 512, 0, stream>>>(
            hin, offsets, csr, deg_inv, WT2 + (size_t)l * 128 * 256,
            bl + (size_t)l * DD, hout, fcW, fcb, out, last);
        hin = hout;
    }
}

// Round 13
// 342.385 us; speedup vs baseline: 4.2735x; 1.1081x over previous
//
#include <hip/hip_runtime.h>
#include <hip/hip_bf16.h>

#define N_NODES 50000
#define N_EDGES 600000
#define DD 128
#define N_LAYERS 6
#define SCAN_BLOCKS 196   // ceil(50000/256)
#define N_CHUNKS 3125     // 50000 / 16 exactly
#define GEMM_BLOCKS 512   // 512 blocks x 8 waves = 4096 chunks >= 3125

#define XB16_T 1600000
#define PREPW_T 196608
#define PREP_TOTAL (XB16_T + PREPW_T + N_EDGES)

typedef __attribute__((ext_vector_type(8))) short bf16x8;
typedef __attribute__((ext_vector_type(4))) float floatx4;

__device__ __forceinline__ unsigned short f2b(float f) {
    unsigned u = __float_as_uint(f);
    unsigned r = (u + 0x7FFFu + ((u >> 16) & 1u)) >> 16;
    return (unsigned short)r;
}

// ---------------- merged prep (x->bf16, W transpose, count_deg) ----------------
// deg/cursor are zeroed by one hipMemsetAsync before this kernel.

__global__ void prep_all(const float* __restrict__ x, unsigned short* __restrict__ hx,
                         const float* __restrict__ Wl, const float* __restrict__ Wr,
                         unsigned short* __restrict__ WT2,
                         const int* __restrict__ dst, int* __restrict__ deg) {
    int gid = blockIdx.x * blockDim.x + threadIdx.x;
    if (gid < XB16_T) {
        int b = gid * 4;
        float4 v = *(const float4*)(x + b);
        ushort4 o;
        o.x = f2b(v.x); o.y = f2b(v.y); o.z = f2b(v.z); o.w = f2b(v.w);
        *(ushort4*)(hx + b) = o;
    } else if (gid < XB16_T + PREPW_T) {
        int idx = gid - XB16_T;
        int l   = idx >> 15;
        int rem = idx & 32767;
        int n   = rem >> 8;
        int k2  = rem & 255;
        const float* W = (k2 < 128 ? Wl : Wr) + (size_t)l * DD * DD + (size_t)(k2 & 127) * DD + n;
        WT2[idx] = f2b(*W);
    } else if (gid < PREP_TOTAL) {
        int e = gid - (XB16_T + PREPW_T);
        atomicAdd(&deg[dst[e]], 1);
    }
}

// ---------------- CSR build (multi-block, proven-fast) ----------------

__global__ void block_sums(const int* __restrict__ deg, int* __restrict__ bsum) {
    __shared__ int s[256];
    int tid = threadIdx.x;
    int i = blockIdx.x * 256 + tid;
    int v = (i < N_NODES) ? deg[i] : 0;
    s[tid] = v;
    __syncthreads();
    #pragma unroll
    for (int off = 128; off > 0; off >>= 1) {
        if (tid < off) s[tid] += s[tid + off];
        __syncthreads();
    }
    if (tid == 0) bsum[blockIdx.x] = s[0];
}

__global__ void scan_bsums(int* __restrict__ bsum, int* __restrict__ offsets) {
    __shared__ int s[256];
    int tid = threadIdx.x;
    int v = (tid < SCAN_BLOCKS) ? bsum[tid] : 0;
    s[tid] = v;
    __syncthreads();
    for (int off = 1; off < 256; off <<= 1) {
        int t = (tid >= off) ? s[tid - off] : 0;
        __syncthreads();
        s[tid] += t;
        __syncthreads();
    }
    if (tid < SCAN_BLOCKS) bsum[tid] = s[tid] - v;   // exclusive
    if (tid == 0) offsets[N_NODES] = N_EDGES;
}

__global__ void write_offsets(const int* __restrict__ deg, const int* __restrict__ bsum,
                              int* __restrict__ offsets, float* __restrict__ deg_inv) {
    __shared__ int s[256];
    int tid = threadIdx.x;
    int i = blockIdx.x * 256 + tid;
    int v = (i < N_NODES) ? deg[i] : 0;
    s[tid] = v;
    __syncthreads();
    for (int off = 1; off < 256; off <<= 1) {
        int t = (tid >= off) ? s[tid - off] : 0;
        __syncthreads();
        s[tid] += t;
        __syncthreads();
    }
    if (i < N_NODES) {
        offsets[i] = bsum[blockIdx.x] + s[tid] - v;
        deg_inv[i] = 1.0f / (float)(v > 1 ? v : 1);
    }
}

__global__ void fill_csr(const int* __restrict__ src, const int* __restrict__ dst,
                         const int* __restrict__ offsets, int* __restrict__ cursor,
                         int* __restrict__ csr_src) {
    int e = blockIdx.x * blockDim.x + threadIdx.x;
    if (e < N_EDGES) {
        int d = dst[e];
        int p = atomicAdd(&cursor[d], 1);
        csr_src[offsets[d] + p] = src[e];
    }
}

// ---------------- FUSED layer: gather-aggregate in registers + MFMA ----------------
// R9-proven (343.6 us best measured). 2 edges in flight is the VGPR sweet spot:
// 4-deep (R12) regressed +6 us/layer from register pressure. Lane (l15,q)
// aggregates node row0+l15's A-fragment features in 32 f32 regs, scales by
// deg_inv, packs with f2b; root H fragments read directly; B from swizzled sW.

__device__ __forceinline__ void acc8(float* a, const uint4& v) {
    a[0] += __uint_as_float(v.x << 16); a[1] += __uint_as_float(v.x & 0xFFFF0000u);
    a[2] += __uint_as_float(v.y << 16); a[3] += __uint_as_float(v.y & 0xFFFF0000u);
    a[4] += __uint_as_float(v.z << 16); a[5] += __uint_as_float(v.z & 0xFFFF0000u);
    a[6] += __uint_as_float(v.w << 16); a[7] += __uint_as_float(v.w & 0xFFFF0000u);
}

__launch_bounds__(512, 4)
__global__ void sage_layer(const unsigned short* __restrict__ hin,
                           const int* __restrict__ offsets,
                           const int* __restrict__ csr_src,
                           const float* __restrict__ deg_inv,
                           const unsigned short* __restrict__ WT2,   // [128 n][256 k]
                           const float* __restrict__ bias,
                           unsigned short* __restrict__ hout,
                           const float* __restrict__ fcW,
                           const float* __restrict__ fcb,
                           float* __restrict__ out,
                           int doFC) {
    __shared__ __align__(16) unsigned short sW[128 * 256];     // 64 KB

    int tid  = threadIdx.x;
    int wid  = tid >> 6, lane = tid & 63;
    int l15  = lane & 15, q = lane >> 4;

    // ---- fill sW (swizzled: chunk c of col stored at col*32 + (c ^ (col&7))) ----
    for (int t = tid; t < 4096; t += 512) {
        int col = t >> 5, c = t & 31;
        uint4 v = *(const uint4*)(WT2 + (size_t)col * 256 + c * 8);
        *(uint4*)(sW + ((size_t)col * 32 + (c ^ (col & 7))) * 8) = v;
    }
    __syncthreads();

    int chunk = wid * GEMM_BLOCKS + (int)blockIdx.x;
    bool active = chunk < N_CHUNKS;
    int chunkC = active ? chunk : N_CHUNKS - 1;   // clamped -> safe addresses
    int row0 = chunkC * 16;
    int node = row0 + l15;

    // ---- in-register aggregation of this lane's A-fragment features ----
    float a[32];
    #pragma unroll
    for (int i = 0; i < 32; ++i) a[i] = 0.f;

    int s0 = active ? offsets[node]     : 0;
    int e0 = active ? offsets[node + 1] : 0;
    float di = deg_inv[node];

    const unsigned short* hbase = hin + q * 8;
    int j = s0;
    for (; j + 1 < e0; j += 2) {
        int src1 = csr_src[j];
        int src2 = csr_src[j + 1];
        const unsigned short* r1 = hbase + (size_t)src1 * DD;
        const unsigned short* r2 = hbase + (size_t)src2 * DD;
        uint4 v0 = *(const uint4*)(r1);
        uint4 v1 = *(const uint4*)(r1 + 32);
        uint4 v2 = *(const uint4*)(r1 + 64);
        uint4 v3 = *(const uint4*)(r1 + 96);
        uint4 w0 = *(const uint4*)(r2);
        uint4 w1 = *(const uint4*)(r2 + 32);
        uint4 w2 = *(const uint4*)(r2 + 64);
        uint4 w3 = *(const uint4*)(r2 + 96);
        acc8(a +  0, v0); acc8(a +  8, v1); acc8(a + 16, v2); acc8(a + 24, v3);
        acc8(a +  0, w0); acc8(a +  8, w1); acc8(a + 16, w2); acc8(a + 24, w3);
    }
    if (j < e0) {
        int src1 = csr_src[j];
        const unsigned short* r1 = hbase + (size_t)src1 * DD;
        uint4 v0 = *(const uint4*)(r1);
        uint4 v1 = *(const uint4*)(r1 + 32);
        uint4 v2 = *(const uint4*)(r1 + 64);
        uint4 v3 = *(const uint4*)(r1 + 96);
        acc8(a +  0, v0); acc8(a +  8, v1); acc8(a + 16, v2); acc8(a + 24, v3);
    }

    // ---- pack A-fragments: agg (s<4, bf16-rounded mean) and root H (s>=4) ----
    bf16x8 aF[8];
    #pragma unroll
    for (int s = 0; s < 4; ++s) {
        bf16x8 f;
        #pragma unroll
        for (int k = 0; k < 8; ++k) f[k] = (short)f2b(a[s * 8 + k] * di);
        aF[s] = f;
    }
    const unsigned short* Hrow = hin + (size_t)node * DD;
    #pragma unroll
    for (int s = 4; s < 8; ++s)
        aF[s] = *(const bf16x8*)(Hrow + (s - 4) * 32 + q * 8);

    float bcol[8];
    #pragma unroll
    for (int jj = 0; jj < 8; ++jj) bcol[jj] = bias[jj * 16 + l15];

    floatx4 acc[8];
    #pragma unroll
    for (int jj = 0; jj < 8; ++jj) acc[jj] = (floatx4){0.f, 0.f, 0.f, 0.f};

    #pragma unroll
    for (int s = 0; s < 8; ++s) {
        int cglob = s * 4 + q;
        #pragma unroll
        for (int jj = 0; jj < 8; ++jj) {
            int col = jj * 16 + l15;
            bf16x8 bF = *(const bf16x8*)(sW + ((size_t)col * 32 + (cglob ^ (col & 7))) * 8);
            acc[jj] = __builtin_amdgcn_mfma_f32_16x16x32_bf16(aF[s], bF, acc[jj], 0, 0, 0);
        }
    }

    if (!doFC) {
        if (active) {
            #pragma unroll
            for (int r = 0; r < 4; ++r) {
                int row = row0 + q * 4 + r;
                #pragma unroll
                for (int jj = 0; jj < 8; ++jj) {
                    float v = acc[jj][r] + bcol[jj];
                    hout[(size_t)row * DD + jj * 16 + l15] = f2b(fmaxf(v, 0.f));
                }
            }
        }
    } else {
        float2 fcw[8];
        #pragma unroll
        for (int jj = 0; jj < 8; ++jj) fcw[jj] = *(const float2*)(fcW + (jj * 16 + l15) * 2);
        float fb0 = fcb[0], fb1 = fcb[1];
        #pragma unroll
        for (int r = 0; r < 4; ++r) {
            float p0 = 0.f, p1 = 0.f;
            #pragma unroll
            for (int jj = 0; jj < 8; ++jj) {
                float v = fmaxf(acc[jj][r] + bcol[jj], 0.f);
                p0 += v * fcw[jj].x;
                p1 += v * fcw[jj].y;
            }
            p0 += __shfl_xor(p0, 1, 64); p1 += __shfl_xor(p1, 1, 64);
            p0 += __shfl_xor(p0, 2, 64); p1 += __shfl_xor(p1, 2, 64);
            p0 += __shfl_xor(p0, 4, 64); p1 += __shfl_xor(p1, 4, 64);
            p0 += __shfl_xor(p0, 8, 64); p1 += __shfl_xor(p1, 8, 64);
            if (l15 == 0 && active) {
                int row = row0 + q * 4 + r;
                out[row * 2]     = p0 + fb0;
                out[row * 2 + 1] = p1 + fb1;
            }
        }
    }
}

// ---------------- launch ----------------

extern "C" void kernel_launch(void* const* d_in, const int* in_sizes, int n_in,
                              void* d_out, int out_size, void* d_ws, size_t ws_size,
                              hipStream_t stream) {
    const float* x    = (const float*)d_in[0];
    const int*   ei   = (const int*)d_in[1];
    const float* Wl   = (const float*)d_in[2];
    const float* Wr   = (const float*)d_in[3];
    const float* bl   = (const float*)d_in[4];
    const float* fcW  = (const float*)d_in[5];
    const float* fcb  = (const float*)d_in[6];
    float* out = (float*)d_out;

    const int* srcIdx = ei;
    const int* dstIdx = ei + N_EDGES;

    char* ws = (char*)d_ws;
    size_t off = 0;
    auto bump = [&](size_t bytes) { char* p = ws + off; off = (off + bytes + 255) & ~(size_t)255; return p; };
    int*   deg     = (int*)  bump(N_NODES * 4);
    int*   cursor  = (int*)  bump(N_NODES * 4);
    int*   offsets = (int*)  bump((N_NODES + 1) * 4);
    int*   bsum    = (int*)  bump(SCAN_BLOCKS * 4);
    float* deg_inv = (float*)bump(N_NODES * 4);
    int*   csr     = (int*)  bump(N_EDGES * 4);
    unsigned short* hx   = (unsigned short*)bump((size_t)N_NODES * DD * 2);
    unsigned short* hb0  = (unsigned short*)bump((size_t)N_NODES * DD * 2);
    unsigned short* hb1  = (unsigned short*)bump((size_t)N_NODES * DD * 2);
    unsigned short* WT2  = (unsigned short*)bump((size_t)N_LAYERS * 128 * 256 * 2);
    (void)ws_size;

    // zero deg+cursor (contiguous in ws) via one stream-ordered memset (~0.4 MB)
    size_t zbytes = (size_t)((char*)cursor - (char*)deg) + (size_t)N_NODES * 4;
    (void)hipMemsetAsync(deg, 0, zbytes, stream);

    prep_all<<<(PREP_TOTAL + 255) / 256, 256, 0, stream>>>(x, hx, Wl, Wr, WT2, dstIdx, deg);
    block_sums<<<SCAN_BLOCKS, 256, 0, stream>>>(deg, bsum);
    scan_bsums<<<1, 256, 0, stream>>>(bsum, offsets);
    write_offsets<<<SCAN_BLOCKS, 256, 0, stream>>>(deg, bsum, offsets, deg_inv);
    fill_csr<<<(N_EDGES + 255) / 256, 256, 0, stream>>>(srcIdx, dstIdx, offsets, cursor, csr);

    const unsigned short* hin = hx;
    unsigned short* hbuf[2] = { hb0, hb1 };
    for (int l = 0; l < N_LAYERS; ++l) {
        int last = (l == N_LAYERS - 1);
        unsigned short* hout = hbuf[l & 1];
        sage_layer<<<GEMM_BLOCKS, 512, 0, stream>>>(
            hin, offsets, csr, deg_inv, WT2 + (size_t)l * 128 * 256,
            bl + (size_t)l * DD, hout, fcW, fcb, out, last);
        hin = hout;
    }
}